// Round 5
// baseline (94.157 us; speedup 1.0000x reference)
//
#include <hip/hip_runtime.h>

// BSpline evaluation, MI355X.
// t [2048] f32 sorted, c [512,2048] f32, delta [1] i32.
// out = sample_points [S] ++ spline_values [S, DIM]; S=32768, DIM=512.
// B rows have <=4 nonzeros (cols j-3..j, j = knot span), incl. the reference's
// stale-column quirk (col i final degree = min(3, NK-1-i)).
// R5: eval wave = 8-sample group x full row (2 float4/lane); hierarchical
// span-uniformity fallback (8 -> 4 -> 1); scalar j/b loads; NT stores.

#define DEG 3

typedef float vfloat4 __attribute__((ext_vector_type(4)));

__device__ __forceinline__ float kn(const float* __restrict__ t, int i) {
    return (i < DEG + 1) ? 0.0f : t[i - (DEG + 1)];
}

// ---------------- fused prep: transpose c + per-sample weights ----------------
#define TILE 32
__global__ __launch_bounds__(256) void prep_kernel(
    const float* __restrict__ c, float* __restrict__ cT,
    const float* __restrict__ t, const int* __restrict__ delta_p,
    float* __restrict__ out_pts, int* __restrict__ jbuf,
    vfloat4* __restrict__ bbuf, int S, int NK, int DIM, int TB)
{
    if ((int)blockIdx.x < TB) {
        __shared__ float tile[TILE][TILE + 1];
        int bx = blockIdx.x % (NK / TILE);
        int by = blockIdx.x / (NK / TILE);
        int tx = threadIdx.x % TILE;
        int ty = threadIdx.x / TILE;         // 0..7
        int x = bx * TILE + tx;
        int y = by * TILE + ty;
        #pragma unroll
        for (int i = 0; i < TILE; i += 8)
            tile[ty + i][tx] = c[(size_t)(y + i) * NK + x];
        __syncthreads();
        int x2 = by * TILE + tx;
        int y2 = bx * TILE + ty;
        #pragma unroll
        for (int i = 0; i < TILE; i += 8)
            cT[(size_t)(y2 + i) * DIM + x2] = tile[tx][ty + i];
        return;
    }

    int s = (blockIdx.x - TB) * blockDim.x + threadIdx.x;
    if (s >= S) return;
    const float delta = (float)(*delta_p);
    const float sv = (float)s * delta;
    out_pts[s] = sv;

    // rightmost j in [DEG, NK+DEG-1] with kn(j) <= sv
    int lo = DEG, hi = NK + DEG - 1;
    while (lo < hi) {
        int mid = (lo + hi + 1) >> 1;
        if (kn(t, mid) <= sv) lo = mid; else hi = mid - 1;
    }
    const int j = lo;

    if (j >= NK) {  // beyond last degree-0 span: B row identically zero
        jbuf[s] = NK - 1;                    // valid row ptr; b=0 makes output 0
        bbuf[s] = (vfloat4){0.f, 0.f, 0.f, 0.f};
        return;
    }

    // Cox-de Boor triangle: N[d][k] = val(j-d+k, d), where(denom==0 -> 0)
    float N[DEG + 1][DEG + 1];
    N[0][0] = 1.0f;
    #pragma unroll
    for (int d = 1; d <= DEG; ++d) {
        #pragma unroll
        for (int k = 0; k <= d; ++k) {
            int i = j - d + k;
            float vpi  = (k >= 1) ? N[d - 1][k - 1] : 0.0f;
            float vpi1 = (k <= d - 1) ? N[d - 1][k] : 0.0f;
            float ki   = kn(t, i);
            float kid  = kn(t, i + d);
            float ki1  = kn(t, i + 1);
            float kid1 = kn(t, i + d + 1);
            float den1 = kid - ki;
            float den2 = kid1 - ki1;
            float w1 = (den1 != 0.0f) ? (sv - ki) / den1 : 0.0f;
            float w2 = (den2 != 0.0f) ? (kid1 - sv) / den2 : 0.0f;
            N[d][k] = w1 * vpi + w2 * vpi1;
        }
    }

    // stale-column quirk: col i keeps degree min(DEG, NK-1-i)
    float b[DEG + 1];
    #pragma unroll
    for (int m = 0; m <= DEG; ++m) {
        int col = j - DEG + m;
        int deg = NK - 1 - col; if (deg > DEG) deg = DEG;
        int idx = m - DEG + deg;
        b[m] = (idx >= 0) ? N[deg][idx] : 0.0f;
    }
    jbuf[s] = j;
    bbuf[s] = (vfloat4){b[0], b[1], b[2], b[3]};
}

// ---------------- streaming eval ----------------
// One wave = 8 consecutive samples x full DIM row. Lane owns float4 columns
// d=lane and d=lane+64 (nvec=128). All j/b wave-uniform scalar loads; span
// branches wave-uniform. Fast path: 8 loads -> 16 NT stores.
__device__ __forceinline__ vfloat4 dot4(const vfloat4 b, const vfloat4 a0,
                                        const vfloat4 a1, const vfloat4 a2,
                                        const vfloat4 a3) {
    return b.x * a0 + b.y * a1 + b.z * a2 + b.w * a3;
}

__global__ __launch_bounds__(256) void bspline_eval(
    const int* __restrict__ jbuf, const vfloat4* __restrict__ bbuf,
    const float* __restrict__ cT, vfloat4* __restrict__ out_spline,
    int DIM)
{
    const int nvec = DIM >> 2;                       // 128
    int gtid = blockIdx.x * blockDim.x + threadIdx.x;
    int wid  = gtid >> 6;
    int lane = gtid & 63;
    int s0   = __builtin_amdgcn_readfirstlane(wid << 3);

    int j[8];
    vfloat4 b[8];
    #pragma unroll
    for (int m = 0; m < 8; ++m) { j[m] = jbuf[s0 + m]; b[m] = bbuf[s0 + m]; }

    vfloat4* orow = out_spline + (size_t)s0 * nvec + lane;

    if (j[0] == j[7]) {
        // whole group shares the span: 4 rows x 2 halves -> 16 outputs
        const vfloat4* r = (const vfloat4*)(cT + (size_t)(j[0] - 3) * DIM) + lane;
        vfloat4 a0 = r[0],        a0b = r[64];
        vfloat4 a1 = r[nvec],     a1b = r[nvec + 64];
        vfloat4 a2 = r[2 * nvec], a2b = r[2 * nvec + 64];
        vfloat4 a3 = r[3 * nvec], a3b = r[3 * nvec + 64];
        #pragma unroll
        for (int m = 0; m < 8; ++m) {
            __builtin_nontemporal_store(dot4(b[m], a0,  a1,  a2,  a3 ), orow + m * nvec);
            __builtin_nontemporal_store(dot4(b[m], a0b, a1b, a2b, a3b), orow + m * nvec + 64);
        }
    } else {
        #pragma unroll
        for (int h = 0; h < 2; ++h) {
            const int m0 = h * 4;
            if (j[m0] == j[m0 + 3]) {
                const vfloat4* r = (const vfloat4*)(cT + (size_t)(j[m0] - 3) * DIM) + lane;
                vfloat4 a0 = r[0],        a0b = r[64];
                vfloat4 a1 = r[nvec],     a1b = r[nvec + 64];
                vfloat4 a2 = r[2 * nvec], a2b = r[2 * nvec + 64];
                vfloat4 a3 = r[3 * nvec], a3b = r[3 * nvec + 64];
                #pragma unroll
                for (int m = m0; m < m0 + 4; ++m) {
                    __builtin_nontemporal_store(dot4(b[m], a0,  a1,  a2,  a3 ), orow + m * nvec);
                    __builtin_nontemporal_store(dot4(b[m], a0b, a1b, a2b, a3b), orow + m * nvec + 64);
                }
            } else {
                #pragma unroll
                for (int m = m0; m < m0 + 4; ++m) {
                    const vfloat4* r = (const vfloat4*)(cT + (size_t)(j[m] - 3) * DIM) + lane;
                    vfloat4 a0 = r[0],        a0b = r[64];
                    vfloat4 a1 = r[nvec],     a1b = r[nvec + 64];
                    vfloat4 a2 = r[2 * nvec], a2b = r[2 * nvec + 64];
                    vfloat4 a3 = r[3 * nvec], a3b = r[3 * nvec + 64];
                    __builtin_nontemporal_store(dot4(b[m], a0,  a1,  a2,  a3 ), orow + m * nvec);
                    __builtin_nontemporal_store(dot4(b[m], a0b, a1b, a2b, a3b), orow + m * nvec + 64);
                }
            }
        }
    }
}

extern "C" void kernel_launch(void* const* d_in, const int* in_sizes, int n_in,
                              void* d_out, int out_size, void* d_ws, size_t ws_size,
                              hipStream_t stream) {
    const float* t = (const float*)d_in[0];
    const float* c = (const float*)d_in[1];
    const int* delta = (const int*)d_in[2];
    const int NK = in_sizes[0];                 // 2048
    const int DIM = in_sizes[1] / NK;           // 512
    const int S = out_size / (1 + DIM);         // 32768

    float* cT = (float*)d_ws;                                  // NK*DIM f32 = 4 MB
    int* jbuf = (int*)((char*)d_ws + (size_t)NK * DIM * 4);    // S ints
    vfloat4* bbuf = (vfloat4*)((char*)jbuf + (size_t)S * 4);   // S vfloat4

    const int TB = (NK / TILE) * (DIM / TILE);  // transpose blocks: 64*16=1024
    const int WB = (S + 255) / 256;             // weights blocks: 128
    prep_kernel<<<TB + WB, 256, 0, stream>>>(
        c, cT, t, delta, (float*)d_out, jbuf, bbuf, S, NK, DIM, TB);

    // one wave per 8-sample group: S/8 waves = S*8 threads
    int total_threads = (S >> 3) * 64;          // 262144
    bspline_eval<<<total_threads / 256, 256, 0, stream>>>(
        jbuf, bbuf, cT, (vfloat4*)((float*)d_out + S), DIM);
}